// Round 1
// baseline (216.933 us; speedup 1.0000x reference)
//
#include <hip/hip_runtime.h>
#include <math.h>

#define BB 128
#define FF 256
#define NN 2000

// -------- Kernel A: glb[b,f] = max_n x[b,f,n]  (one wave per row) --------
__global__ __launch_bounds__(256) void k_max(const float* __restrict__ x,
                                             float* __restrict__ glb) {
    int gid  = blockIdx.x * blockDim.x + threadIdx.x;
    int wave = gid >> 6;
    int lane = threadIdx.x & 63;
    if (wave >= BB * FF) return;
    const float4* r4 = (const float4*)(x + (size_t)wave * NN);  // 8000B rows, 16B aligned
    float m = -INFINITY;
    for (int i = lane; i < NN / 4; i += 64) {
        float4 v = r4[i];
        m = fmaxf(m, fmaxf(fmaxf(v.x, v.y), fmaxf(v.z, v.w)));
    }
#pragma unroll
    for (int off = 32; off > 0; off >>= 1) m = fmaxf(m, __shfl_xor(m, off));
    if (lane == 0) glb[wave] = m;
}

// -------- Kernel B: per-batch dense prep -> cK[b,f], cK0[b] --------
__global__ __launch_bounds__(256) void k_prep(
    const float* __restrict__ x, const int* __restrict__ lc,
    const float* __restrict__ glb,
    const float* __restrict__ Wg, const float* __restrict__ bg,
    const float* __restrict__ Wnode, const float* __restrict__ bnode,
    const float* __restrict__ Wlc, const float* __restrict__ blc,
    float* __restrict__ cK, float* __restrict__ cK0)
{
    int b = blockIdx.x;
    int f = threadIdx.x;  // 0..255
    __shared__ float s_glb[FF], s_ctx[2 * FF], s_cQ[FF], s_red[FF];
    const float* xb = x + (size_t)b * FF * NN;
    s_glb[f] = glb[b * FF + f];
    int l0 = lc[2 * b], l1 = lc[2 * b + 1];
    s_ctx[f]      = xb[(size_t)f * NN + l0];
    s_ctx[FF + f] = xb[(size_t)f * NN + l1];
    __syncthreads();
    // Q[f] = Wg[f,:] . glb + bg[f]
    float q = bg[f];
    const float* wg = Wg + (size_t)f * FF;
    for (int j = 0; j < FF; ++j) q = fmaf(wg[j], s_glb[j], q);
    // cQ[f] = Wlc[f,:] . ctx + blc[f] + Q[f]
    float cq = blc[f] + q;
    const float* wl = Wlc + (size_t)f * 2 * FF;
    for (int j = 0; j < 2 * FF; ++j) cq = fmaf(wl[j], s_ctx[j], cq);
    s_cQ[f]  = cq;
    s_red[f] = cq * bnode[f];
    __syncthreads();
    // cK[f] = sum_g cQ[g] * WnodeK[g,f]   (column access, coalesced across threads)
    float ck = 0.f;
    for (int g = 0; g < FF; ++g) ck = fmaf(s_cQ[g], Wnode[(size_t)g * FF + f], ck);
    cK[b * FF + f] = ck;
    // cK0 = cQ . bnodeK
    for (int s = 128; s > 0; s >>= 1) {
        if (f < s) s_red[f] += s_red[f + s];
        __syncthreads();
    }
    if (f == 0) cK0[b] = s_red[0];
}

// -------- Kernel C: one block per batch: ucj -> softmax -> y -> dense -> logits --------
__global__ __launch_bounds__(1024) void k_main(
    const float* __restrict__ x,
    const float* __restrict__ cK, const float* __restrict__ cK0,
    const float* __restrict__ Wnode, const float* __restrict__ bnode,
    const float* __restrict__ Wproj, const float* __restrict__ bproj,
    float* __restrict__ out)
{
    int b    = blockIdx.x;
    int tid  = threadIdx.x;
    int wid  = tid >> 6;
    int lane = tid & 63;
    const float* xb = x + (size_t)b * FF * NN;

    __shared__ float s_cK[FF];
    __shared__ float s_p[NN];
    __shared__ float s_y[FF];
    __shared__ float s_v[FF];
    __shared__ float s_cL[FF];
    __shared__ float s_red[40];
    const float scale = 0.0625f;  // 1/sqrt(256)

    if (tid < FF) s_cK[tid] = cK[b * FF + tid];
    __syncthreads();

    // ---- phase 1: ucj for n = 2*tid, 2*tid+1 ----
    float u0 = -INFINITY, u1 = -INFINITY;
    if (tid < NN / 2) {
        float a0 = 0.f, a1 = 0.f;
        const float* xp = xb + 2 * tid;
#pragma unroll 4
        for (int f = 0; f < FF; ++f) {
            float2 v = *(const float2*)(xp + (size_t)f * NN);
            float  c = s_cK[f];
            a0 = fmaf(c, v.x, a0);
            a1 = fmaf(c, v.y, a1);
        }
        float k0 = cK0[b];
        u0 = (a0 + k0) * scale;
        u1 = (a1 + k0) * scale;
    }
    // block max
    float m = fmaxf(u0, u1);
#pragma unroll
    for (int off = 32; off > 0; off >>= 1) m = fmaxf(m, __shfl_xor(m, off));
    if (lane == 0) s_red[wid] = m;
    __syncthreads();
    if (tid == 0) {
        float mm = s_red[0];
        for (int w = 1; w < 16; ++w) mm = fmaxf(mm, s_red[w]);
        s_red[32] = mm;
    }
    __syncthreads();
    float bm = s_red[32];
    float p0 = 0.f, p1 = 0.f;
    if (tid < NN / 2) {
        p0 = __expf(u0 - bm);
        p1 = __expf(u1 - bm);
        s_p[2 * tid]     = p0;
        s_p[2 * tid + 1] = p1;
    }
    float ps = p0 + p1;
#pragma unroll
    for (int off = 32; off > 0; off >>= 1) ps += __shfl_xor(ps, off);
    __syncthreads();           // all reads of s_red[0..15] (max phase) done
    if (lane == 0) s_red[wid] = ps;
    __syncthreads();
    if (tid == 0) {
        float ss = 0.f;
        for (int w = 0; w < 16; ++w) ss += s_red[w];
        s_red[33] = ss;
    }
    __syncthreads();
    float inv_sum = 1.0f / s_red[33];

    // ---- phase 2: y[f] = (sum_n p[n]*x[f,n]) * inv_sum  (wave per f, L2-resident reread) ----
    const float4* p4 = (const float4*)s_p;
    for (int f = wid; f < FF; f += 16) {
        const float4* r4 = (const float4*)(xb + (size_t)f * NN);
        float acc = 0.f;
        for (int i = lane; i < NN / 4; i += 64) {
            float4 xv = r4[i];
            float4 pv = p4[i];
            acc = fmaf(xv.x, pv.x, acc);
            acc = fmaf(xv.y, pv.y, acc);
            acc = fmaf(xv.z, pv.z, acc);
            acc = fmaf(xv.w, pv.w, acc);
        }
#pragma unroll
        for (int off = 32; off > 0; off >>= 1) acc += __shfl_xor(acc, off);
        if (lane == 0) s_y[f] = acc * inv_sum;
    }
    __syncthreads();

    // ---- phase 3: small dense chain ----
    if (tid < FF) {  // nc_pre[g] = WnodeV[g,:] . y + bnodeV[g]
        float a = bnode[FF + tid];
        const float* w = Wnode + (size_t)(FF + tid) * FF;
        for (int j = 0; j < FF; ++j) a = fmaf(w[j], s_y[j], a);
        s_v[tid] = a;
    }
    __syncthreads();
    float nc2 = 0.f;
    if (tid < FF) {  // nc2[i] = Wproj[i,:] . nc_pre + bproj[i]
        nc2 = bproj[tid];
        const float* w = Wproj + (size_t)tid * FF;
        for (int j = 0; j < FF; ++j) nc2 = fmaf(w[j], s_v[j], nc2);
    }
    __syncthreads();
    if (tid < FF) s_v[tid] = nc2;
    __syncthreads();
    if (tid < FF) {  // cL[f] = sum_g nc2[g]*WnodeL[g,f];  cL0 = nc2 . bnodeL
        float cl = 0.f;
        for (int g = 0; g < FF; ++g) cl = fmaf(s_v[g], Wnode[(size_t)(2 * FF + g) * FF + tid], cl);
        s_cL[tid] = cl;
        float t = nc2 * bnode[2 * FF + tid];
#pragma unroll
        for (int off = 32; off > 0; off >>= 1) t += __shfl_xor(t, off);
        if (lane == 0) s_red[wid] = t;  // wid 0..3
    }
    __syncthreads();
    if (tid == 0) s_red[34] = s_red[0] + s_red[1] + s_red[2] + s_red[3];
    __syncthreads();
    float cl0 = s_red[34];

    // ---- phase 4: logits + tanh ----
    if (tid < NN / 2) {
        float a0 = 0.f, a1 = 0.f;
        const float* xp = xb + 2 * tid;
#pragma unroll 4
        for (int f = 0; f < FF; ++f) {
            float2 v = *(const float2*)(xp + (size_t)f * NN);
            float  c = s_cL[f];
            a0 = fmaf(c, v.x, a0);
            a1 = fmaf(c, v.y, a1);
        }
        float l0 = (a0 + cl0) * scale;
        float l1 = (a1 + cl0) * scale;
        out[b * NN + 2 * tid]     = tanhf(l0) * 10.f;
        out[b * NN + 2 * tid + 1] = tanhf(l1) * 10.f;
    }
}

extern "C" void kernel_launch(void* const* d_in, const int* in_sizes, int n_in,
                              void* d_out, int out_size, void* d_ws, size_t ws_size,
                              hipStream_t stream) {
    const float* x     = (const float*)d_in[0];
    const int*   lc    = (const int*)d_in[1];
    const float* Wg    = (const float*)d_in[2];
    const float* bg    = (const float*)d_in[3];
    const float* Wnode = (const float*)d_in[4];
    const float* bnode = (const float*)d_in[5];
    const float* Wlc   = (const float*)d_in[6];
    const float* blc   = (const float*)d_in[7];
    const float* Wproj = (const float*)d_in[8];
    const float* bproj = (const float*)d_in[9];
    float* out = (float*)d_out;

    float* ws  = (float*)d_ws;
    float* glb = ws;                 // B*F
    float* cK  = ws + BB * FF;       // B*F
    float* cK0 = ws + 2 * BB * FF;   // B

    k_max <<<BB * FF / 4, 256, 0, stream>>>(x, glb);
    k_prep<<<BB, 256, 0, stream>>>(x, lc, glb, Wg, bg, Wnode, bnode, Wlc, blc, cK, cK0);
    k_main<<<BB, 1024, 0, stream>>>(x, cK, cK0, Wnode, bnode, Wproj, bproj, out);
}